// Round 3
// baseline (1528.019 us; speedup 1.0000x reference)
//
#include <hip/hip_runtime.h>
#include <hip/hip_bf16.h>
#include <hip/hip_fp16.h>

typedef _Float16 half8 __attribute__((ext_vector_type(8)));
typedef _Float16 half4 __attribute__((ext_vector_type(4)));
typedef float floatx4 __attribute__((ext_vector_type(4)));

__device__ __forceinline__ _Float16 f2h(float f) { return (_Float16)f; }

// ---------------------------------------------------------------------------
// counting-sort of edges by dst
// ---------------------------------------------------------------------------
__global__ void hist_kernel(const int* __restrict__ dst, int* __restrict__ cnt, int E)
{
    int e = blockIdx.x * 256 + threadIdx.x;
    if (e < E) atomicAdd(&cnt[dst[e]], 1);
}

__global__ void scan1_kernel(int* __restrict__ data, int n, int* __restrict__ blockSums)
{
    __shared__ int sm[256];
    const int t = threadIdx.x;
    const int base = blockIdx.x * 1024 + t * 4;
    int v[4]; int s = 0;
#pragma unroll
    for (int i = 0; i < 4; ++i) { v[i] = (base + i < n) ? data[base + i] : 0; s += v[i]; }
    sm[t] = s; __syncthreads();
#pragma unroll
    for (int off = 1; off < 256; off <<= 1) {
        int y = (t >= off) ? sm[t - off] : 0;
        __syncthreads();
        if (t >= off) sm[t] += y;
        __syncthreads();
    }
    int excl = sm[t] - s;
    if (t == 255) blockSums[blockIdx.x] = sm[255];
    int run = excl;
#pragma unroll
    for (int i = 0; i < 4; ++i) {
        if (base + i < n) data[base + i] = run;
        run += v[i];
    }
}

__global__ void scan2_kernel(int* __restrict__ blockSums, int nb)
{
    __shared__ int sm[256];
    const int t = threadIdx.x;
    int s = (t < nb) ? blockSums[t] : 0;
    sm[t] = s; __syncthreads();
#pragma unroll
    for (int off = 1; off < 256; off <<= 1) {
        int y = (t >= off) ? sm[t - off] : 0;
        __syncthreads();
        if (t >= off) sm[t] += y;
        __syncthreads();
    }
    if (t < nb) blockSums[t] = sm[t] - s;
}

__global__ void scan3_kernel(int* __restrict__ data, int n, const int* __restrict__ blockSums)
{
    const int base = blockIdx.x * 1024 + threadIdx.x * 4;
    const int add = blockSums[blockIdx.x];
#pragma unroll
    for (int i = 0; i < 4; ++i)
        if (base + i < n) data[base + i] += add;
}

__global__ void scatter_kernel(const int* __restrict__ src, const int* __restrict__ dst,
                               const float* __restrict__ w, int* __restrict__ cursor,
                               int* __restrict__ srcS, int* __restrict__ dstS,
                               half4* __restrict__ wS4, int E)
{
    int e = blockIdx.x * 256 + threadIdx.x;
    if (e >= E) return;
    int d = dst[e];
    int p = atomicAdd(&cursor[d], 1);
    srcS[p] = src[e];
    dstS[p] = d;
    half4 q;
    q[0] = f2h(w[(size_t)e * 3 + 0]);
    q[1] = f2h(w[(size_t)e * 3 + 1]);
    q[2] = f2h(w[(size_t)e * 3 + 2]);
    q[3] = (_Float16)1.0f;             // constant-1 slot -> bias via MFMA (k=131)
    wS4[p] = q;
}

// ---------------------------------------------------------------------------
// weight prep: W [K,128] fp32 -> out [128,KP] f16, optional bias at col 131
// ---------------------------------------------------------------------------
__global__ void wprep_kernel(const float* __restrict__ W, const float* __restrict__ bias,
                             _Float16* __restrict__ out, int K, int KP)
{
    int idx = blockIdx.x * 256 + threadIdx.x;
    if (idx >= 128 * KP) return;
    int f = idx / KP, k = idx % KP;
    float v = 0.0f;
    if (k < K) v = W[(size_t)k * 128 + f];
    else if (bias != nullptr && k == 131) v = bias[f];
    out[idx] = f2h(v);
}

__global__ void embW1_kernel(const float* __restrict__ emb, const float* __restrict__ W1,
                             const float* __restrict__ b1, float* __restrict__ out, int NGT)
{
    int idx = blockIdx.x * 256 + threadIdx.x;
    if (idx >= NGT * 128) return;
    int g = idx >> 7, f = idx & 127;
    float s = b1[f];
    for (int k = 0; k < 64; ++k) s += emb[g * 64 + k] * W1[(size_t)k * 128 + f];
    out[idx] = s;
}

__global__ void embW2_kernel(const float* __restrict__ emb, const float* __restrict__ W2,
                             float* __restrict__ out, int NGT)
{
    int idx = blockIdx.x * 256 + threadIdx.x;
    if (idx >= NGT * 128) return;
    int g = idx >> 7, f = idx & 127;
    float s = 0.0f;
    for (int k = 0; k < 64; ++k) s += emb[g * 64 + k] * W2[(size_t)k * 128 + f];
    out[idx] = s;
}

// ---------------------------------------------------------------------------
// run-flush helper: one hN row (runD), cols jt*16+lRow, values runV[8]
// ---------------------------------------------------------------------------
template<bool H16>
__device__ __forceinline__ void flushRun(void* hNv, int runD, const float (&runV)[8],
                                         int lRow, int lane)
{
    if (H16) {
        __half* hN = (__half*)hNv;
#pragma unroll
        for (int jt = 0; jt < 8; ++jt) {
            float other = __shfl_xor(runV[jt], 1);          // all lanes execute
            if ((lane & 1) == 0 && (runV[jt] > 0.0f || other > 0.0f)) {
                __half2 v = __halves2half2(__float2half(runV[jt]), __float2half(other));
                unsafeAtomicAdd((__half2*)(hN + (size_t)runD * 128 + jt * 16 + lRow), v);
            }
        }
    } else {
        float* dp = (float*)hNv + (size_t)runD * 128 + lRow;
#pragma unroll
        for (int jt = 0; jt < 8; ++jt)
            if (runV[jt] > 0.0f) unsafeAtomicAdd(dp + jt * 16, runV[jt]);
    }
}

// ---------------------------------------------------------------------------
// edge layer 0 (no MFMA): t = relu(embW1b[gt[src]] + w@W1w); merged atomic add
// ---------------------------------------------------------------------------
template<bool H16>
__global__ void __launch_bounds__(256, 4)
edge0_kernel(const int* __restrict__ gt, const float* __restrict__ embW1b,
             const float* __restrict__ W1_0,
             const int* __restrict__ srcS, const int* __restrict__ dstS,
             const half4* __restrict__ wS4,
             void* __restrict__ hNv, int E, int tilesPerWave, int eTiles)
{
    const int tid  = threadIdx.x;
    const int lane = tid & 63;
    const int wv   = tid >> 6;
    const int lRow = lane & 15;
    const int lGrp = lane >> 4;

    float w1w[3][8];
#pragma unroll
    for (int c = 0; c < 3; ++c)
#pragma unroll
        for (int jt = 0; jt < 8; ++jt)
            w1w[c][jt] = W1_0[(size_t)(64 + c) * 128 + jt * 16 + lRow];

    const int wave = blockIdx.x * 4 + wv;
    const int t0 = wave * tilesPerWave;
    const int t1 = min(t0 + tilesPerWave, eTiles);

    for (int tile = t0; tile < t1; ++tile) {
        const int e0 = tile * 16;
        const int eb = e0 + lGrp * 4;
        int4 s4 = *(const int4*)(srcS + eb);   // padded past E
        int4 d4 = *(const int4*)(dstS + eb);
        const int s4a[4] = {s4.x, s4.y, s4.z, s4.w};
        const int d4a[4] = {d4.x, d4.y, d4.z, d4.w};

        int g4[4]; half4 q4[4];
#pragma unroll
        for (int r = 0; r < 4; ++r) {
            const bool v_ = (eb + r) < E;
            g4[r] = gt[v_ ? s4a[r] : 0];
            q4[r] = wS4[v_ ? (eb + r) : 0];
        }

        int runD; float runV[8];
        {
            const bool v_ = eb < E;
            runD = d4a[0];
            float w0 = (float)q4[0][0], w1 = (float)q4[0][1], w2 = (float)q4[0][2];
#pragma unroll
            for (int jt = 0; jt < 8; ++jt) {
                float m = embW1b[(size_t)g4[0] * 128 + jt * 16 + lRow]
                        + w0 * w1w[0][jt] + w1 * w1w[1][jt] + w2 * w1w[2][jt];
                runV[jt] = v_ ? fmaxf(m, 0.0f) : 0.0f;
            }
        }
#pragma unroll
        for (int r = 1; r < 4; ++r) {
            const bool v_ = (eb + r) < E;
            const int d_ = d4a[r];
            float w0 = (float)q4[r][0], w1 = (float)q4[r][1], w2 = (float)q4[r][2];
            float vr[8];
#pragma unroll
            for (int jt = 0; jt < 8; ++jt) {
                float m = embW1b[(size_t)g4[r] * 128 + jt * 16 + lRow]
                        + w0 * w1w[0][jt] + w1 * w1w[1][jt] + w2 * w1w[2][jt];
                vr[jt] = v_ ? fmaxf(m, 0.0f) : 0.0f;
            }
            if (d_ == runD) {
#pragma unroll
                for (int jt = 0; jt < 8; ++jt) runV[jt] += vr[jt];
            } else {
                flushRun<H16>(hNv, runD, runV, lRow, lane);
                runD = d_;
#pragma unroll
                for (int jt = 0; jt < 8; ++jt) runV[jt] = vr[jt];
            }
        }
        flushRun<H16>(hNv, runD, runV, lRow, lane);
    }
}

// ---------------------------------------------------------------------------
// edge layers 1,2 (MFMA), 2-deep software pipeline
// ---------------------------------------------------------------------------
template<bool H16>
__global__ void __launch_bounds__(512, 4)
edge_mfma_kernel(const _Float16* __restrict__ hA,   // [N,128]
                 const _Float16* __restrict__ W1T,  // [128,160]
                 const int* __restrict__ srcS, const int* __restrict__ dstS,
                 const half4* __restrict__ wS4,
                 void* __restrict__ hNv, int E, int tilesPerWave, int eTiles)
{
    constexpr int KPAD = 160, KC = 5, SPR = 20, LDSK = 192;
    __shared__ __align__(16) _Float16 lds[128 * LDSK];

    const int tid = threadIdx.x;
    for (int s = tid; s < 128 * SPR; s += 512) {
        const int row = s / SPR, seg = s % SPR;
        half8 v = *(const half8*)(W1T + (size_t)row * KPAD + seg * 8);
        *(half8*)(&lds[row * LDSK + ((seg ^ (row & 7)) * 8)]) = v;
    }
    __syncthreads();

    const int lane = tid & 63;
    const int wv   = tid >> 6;
    const int lRow = lane & 15;
    const int lGrp = lane >> 4;
    const int wave = blockIdx.x * 8 + wv;
    const int t0 = wave * tilesPerWave;
    const int t1 = min(t0 + tilesPerWave, eTiles);
    if (t0 >= t1) return;

    auto loadSQ = [&](int tile, int& s_, half4& q) {
        const int eA = min(tile * 16 + lRow, E - 1);
        s_ = srcS[eA];
        q  = wS4[eA];
    };
    auto loadD4 = [&](int tile, int4& d4) {
        d4 = *(const int4*)(dstS + tile * 16 + lGrp * 4);  // padded past E
    };
    auto loadA = [&](int s_, half4 q, half8 (&F)[5]) {
#pragma unroll
        for (int kc = 0; kc < 4; ++kc)
            F[kc] = *(const half8*)(hA + (size_t)s_ * 128 + kc * 32 + lGrp * 8);
        half8 aw = {};
        if (lGrp == 0) { aw[0] = q[0]; aw[1] = q[1]; aw[2] = q[2]; aw[3] = q[3]; }
        F[4] = aw;
    };
    auto compute = [&](const half8 (&F)[5], const int4 d4, int tile) {
        floatx4 acc[8] = {};
#pragma unroll
        for (int jt = 0; jt < 8; ++jt) {
            const int rb = (jt * 16 + lRow) * LDSK;
            const int sw = (jt * 16 + lRow) & 7;
#pragma unroll
            for (int kc = 0; kc < KC; ++kc) {
                half8 b = *(const half8*)(&lds[rb + (((kc * 4 + lGrp) ^ sw) * 8)]);
                acc[jt] = __builtin_amdgcn_mfma_f32_16x16x32_f16(F[kc], b, acc[jt], 0, 0, 0);
            }
        }
        const int eb = tile * 16 + lGrp * 4;
        const int d4a[4] = {d4.x, d4.y, d4.z, d4.w};
        int runD; float runV[8];
        {
            const bool v_ = eb < E;
            runD = d4a[0];
#pragma unroll
            for (int jt = 0; jt < 8; ++jt) runV[jt] = v_ ? fmaxf(acc[jt][0], 0.0f) : 0.0f;
        }
#pragma unroll
        for (int r = 1; r < 4; ++r) {
            const bool v_ = (eb + r) < E;
            const int d_ = d4a[r];
            if (d_ == runD) {
#pragma unroll
                for (int jt = 0; jt < 8; ++jt)
                    runV[jt] += v_ ? fmaxf(acc[jt][r], 0.0f) : 0.0f;
            } else {
                flushRun<H16>(hNv, runD, runV, lRow, lane);
                runD = d_;
#pragma unroll
                for (int jt = 0; jt < 8; ++jt)
                    runV[jt] = v_ ? fmaxf(acc[jt][r], 0.0f) : 0.0f;
            }
        }
        flushRun<H16>(hNv, runD, runV, lRow, lane);
    };

    int   sA_, sB_;  half4 qA_, qB_;  int4 d4A, d4B;
    half8 FA[5], FB[5];

    loadSQ(t0, sA_, qA_);
    loadD4(t0, d4A);
    loadA(sA_, qA_, FA);
    if (t0 + 1 < t1) loadSQ(t0 + 1, sB_, qB_);

    int t = t0;
    while (true) {
        // phase A: current tile t uses FA/d4A
        if (t + 1 < t1) { loadA(sB_, qB_, FB); loadD4(t + 1, d4B); }
        if (t + 2 < t1) loadSQ(t + 2, sA_, qA_);
        compute(FA, d4A, t);
        if (++t >= t1) break;
        // phase B
        if (t + 1 < t1) { loadA(sA_, qA_, FA); loadD4(t + 1, d4A); }
        if (t + 2 < t1) loadSQ(t + 2, sB_, qB_);
        compute(FB, d4B, t);
        if (++t >= t1) break;
    }
}

// ---------------------------------------------------------------------------
// node kernel: h = normalize(relu([h,]hN @ W2 [+ embW2[gt]])); readout
// ---------------------------------------------------------------------------
template<bool H16, bool L0, bool LAST>
__global__ void __launch_bounds__(512, 4)
node_kernel(const _Float16* __restrict__ hA,    // [N,128] (unused if L0)
            const void* __restrict__ hNv,       // [N,128] f16 or f32
            const _Float16* __restrict__ W2T,   // [128,K2]
            const float* __restrict__ embW2,    // [30,128] (L0 only)
            const int* __restrict__ gt,         // (L0 only)
            const int* __restrict__ n2g,
            _Float16* __restrict__ hOut,        // if !LAST
            float* __restrict__ fOut,           // if LAST
            float* __restrict__ readout,
            int N, int tilesPerWave, int nTiles, int layerOff)
{
    constexpr int K2  = L0 ? 128 : 256;
    constexpr int KCA = L0 ? 0 : 4;
    constexpr int KC  = K2 / 32;
    constexpr int SPR = K2 / 8;
    __shared__ __align__(16) _Float16 lds[128 * K2];

    const int tid = threadIdx.x;
    for (int s = tid; s < 128 * SPR; s += 512) {
        const int row = s / SPR, seg = s % SPR;
        half8 v = *(const half8*)(W2T + (size_t)row * K2 + seg * 8);
        *(half8*)(&lds[row * K2 + ((seg ^ (row & 7)) * 8)]) = v;
    }
    __syncthreads();

    const int lane = tid & 63;
    const int wv   = tid >> 6;
    const int lRow = lane & 15;
    const int lGrp = lane >> 4;
    const int wave = blockIdx.x * 8 + wv;
    const int t0 = wave * tilesPerWave;
    const int t1 = min(t0 + tilesPerWave, nTiles);
    if (t0 >= t1) return;

    int gCur = -1; float racc[8];
#pragma unroll
    for (int jt = 0; jt < 8; ++jt) racc[jt] = 0.0f;

    for (int tile = t0; tile < t1; ++tile) {
        const int i0 = tile * 16;
        const int iA = min(i0 + lRow, N - 1);

        half8 afrag[KC];
#pragma unroll
        for (int kc = 0; kc < KCA; ++kc)
            afrag[kc] = *(const half8*)(hA + (size_t)iA * 128 + kc * 32 + lGrp * 8);
        if (H16) {
            const _Float16* hN = (const _Float16*)hNv;
#pragma unroll
            for (int kc = KCA; kc < KC; ++kc)
                afrag[kc] = *(const half8*)(hN + (size_t)iA * 128 + (kc - KCA) * 32 + lGrp * 8);
        } else {
            const float* hN = (const float*)hNv;
#pragma unroll
            for (int kc = KCA; kc < KC; ++kc) {
                const float* p = hN + (size_t)iA * 128 + (kc - KCA) * 32 + lGrp * 8;
                floatx4 f0 = *(const floatx4*)(p);
                floatx4 f1 = *(const floatx4*)(p + 4);
                half8 a;
#pragma unroll
                for (int i = 0; i < 4; ++i) { a[i] = f2h(f0[i]); a[i + 4] = f2h(f1[i]); }
                afrag[kc] = a;
            }
        }

        floatx4 acc[8] = {};
#pragma unroll
        for (int jt = 0; jt < 8; ++jt) {
            const int rb = (jt * 16 + lRow) * K2;
            const int sw = (jt * 16 + lRow) & 7;
#pragma unroll
            for (int kc = 0; kc < KC; ++kc) {
                half8 b = *(const half8*)(&lds[rb + (((kc * 4 + lGrp) ^ sw) * 8)]);
                acc[jt] = __builtin_amdgcn_mfma_f32_16x16x32_f16(afrag[kc], b, acc[jt], 0, 0, 0);
            }
        }

        if (L0) {
#pragma unroll
            for (int r = 0; r < 4; ++r) {
                const int i = min(i0 + lGrp * 4 + r, N - 1);
                const int g_t = gt[i];
#pragma unroll
                for (int jt = 0; jt < 8; ++jt)
                    acc[jt][r] += embW2[(size_t)g_t * 128 + jt * 16 + lRow];
            }
        }

        float scl[4];
#pragma unroll
        for (int r = 0; r < 4; ++r) {
            float s = 0.f;
#pragma unroll
            for (int jt = 0; jt < 8; ++jt) {
                float v = fmaxf(acc[jt][r], 0.0f);
                s += v * v;
            }
#pragma unroll
            for (int m = 1; m <= 8; m <<= 1) s += __shfl_xor(s, m);
            scl[r] = 1.0f / fmaxf(sqrtf(s), 1e-12f);
        }

#pragma unroll
        for (int r = 0; r < 4; ++r) {
            const int i = i0 + lGrp * 4 + r;
            if (i < N) {
#pragma unroll
                for (int jt = 0; jt < 8; ++jt) {
                    float v = fmaxf(acc[jt][r], 0.0f) * scl[r];
                    if (LAST) fOut[(size_t)i * 128 + jt * 16 + lRow] = v;
                    else      hOut[(size_t)i * 128 + jt * 16 + lRow] = f2h(v);
                }
            }
        }

        // readout (sorted n2g): accumulate across same-graph tiles in registers
        const int gFirst = n2g[min(i0, N - 1)];
        const int gLast  = n2g[min(i0 + 15, N - 1)];
        if (gFirst == gLast && i0 + 15 < N) {
            if (gFirst != gCur) {
                if (gCur >= 0 && lane < 16) {
#pragma unroll
                    for (int jt = 0; jt < 8; ++jt)
                        unsafeAtomicAdd(&readout[(size_t)gCur * 384 + layerOff + jt * 16 + lane], racc[jt]);
                }
                gCur = gFirst;
#pragma unroll
                for (int jt = 0; jt < 8; ++jt) racc[jt] = 0.0f;
            }
#pragma unroll
            for (int jt = 0; jt < 8; ++jt) {
                float t = 0.f;
#pragma unroll
                for (int r = 0; r < 4; ++r) t += fmaxf(acc[jt][r], 0.0f) * scl[r];
                t += __shfl_xor(t, 16);
                t += __shfl_xor(t, 32);
                racc[jt] += t;
            }
        } else {
            if (gCur >= 0 && lane < 16) {
#pragma unroll
                for (int jt = 0; jt < 8; ++jt)
                    unsafeAtomicAdd(&readout[(size_t)gCur * 384 + layerOff + jt * 16 + lane], racc[jt]);
            }
            gCur = -1;
#pragma unroll
            for (int jt = 0; jt < 8; ++jt) racc[jt] = 0.0f;
#pragma unroll
            for (int r = 0; r < 4; ++r) {
                const int i = i0 + lGrp * 4 + r;
                if (i < N) {
                    const int g = n2g[i];
#pragma unroll
                    for (int jt = 0; jt < 8; ++jt) {
                        float v = fmaxf(acc[jt][r], 0.0f) * scl[r];
                        unsafeAtomicAdd(&readout[(size_t)g * 384 + layerOff + jt * 16 + lRow], v);
                    }
                }
            }
        }
    }
    if (gCur >= 0 && lane < 16) {
#pragma unroll
        for (int jt = 0; jt < 8; ++jt)
            unsafeAtomicAdd(&readout[(size_t)gCur * 384 + layerOff + jt * 16 + lane], racc[jt]);
    }
}

// ---------------------------------------------------------------------------
extern "C" void kernel_launch(void* const* d_in, const int* in_sizes, int n_in,
                              void* d_out, int out_size, void* d_ws, size_t ws_size,
                              hipStream_t stream)
{
    const int*   gate_type = (const int*)d_in[0];
    const int*   src  = (const int*)d_in[1];
    const int*   dst  = (const int*)d_in[2];
    const float* wE   = (const float*)d_in[3];
    const int*   n2g  = (const int*)d_in[4];
    const float* emb  = (const float*)d_in[5];
    const float* W1_0 = (const float*)d_in[6];
    const float* b1_0 = (const float*)d_in[7];
    const float* W2_0 = (const float*)d_in[8];
    const float* W1_1 = (const float*)d_in[9];
    const float* b1_1 = (const float*)d_in[10];
    const float* W2_1 = (const float*)d_in[11];
    const float* W1_2 = (const float*)d_in[12];
    const float* b1_2 = (const float*)d_in[13];
    const float* W2_2 = (const float*)d_in[14];

    const int N = in_sizes[0];
    const int E = in_sizes[1];
    const int NGT = in_sizes[5] / 64;

    char* ws = (char*)d_ws;
    size_t off = 0;
    auto alloc = [&](size_t bytes) { void* p = ws + off; off = (off + bytes + 255) & ~255ULL; return p; };
    _Float16* hBuf  = (_Float16*)alloc((size_t)N * 128 * 2);
    int*      srcS  = (int*)alloc(((size_t)E + 16) * 4);
    int*      dstS  = (int*)alloc(((size_t)E + 16) * 4);
    half4*    wS4   = (half4*)alloc(((size_t)E + 16) * 8);
    int*      cnt   = (int*)alloc((size_t)N * 4);
    int*      bSums = (int*)alloc(256 * 4);
    _Float16* W1T1  = (_Float16*)alloc((size_t)128 * 160 * 2);
    _Float16* W1T2  = (_Float16*)alloc((size_t)128 * 160 * 2);
    _Float16* W2T0  = (_Float16*)alloc((size_t)128 * 128 * 2);
    _Float16* W2T1  = (_Float16*)alloc((size_t)128 * 256 * 2);
    _Float16* W2T2  = (_Float16*)alloc((size_t)128 * 256 * 2);
    float*    eW1b  = (float*)alloc((size_t)NGT * 128 * 4);
    float*    eW2   = (float*)alloc((size_t)NGT * 128 * 4);
    size_t hn16_off = off;
    const bool h16 = (ws_size >= hn16_off + (size_t)N * 128 * 2 + 256);
    _Float16* hN16 = (_Float16*)alloc((size_t)N * 128 * 2);   // only used if h16

    float* readout = (float*)d_out + (size_t)N * 128;  // [G,384]
    void*  hN      = h16 ? (void*)hN16 : (void*)d_out; // fp32 fallback: d_out

    const int eTiles = (E + 15) / 16;
    const int nTiles = (N + 15) / 16;
    const int EB = 512;                                 // edge blocks (512 thr)
    const int tpwE = (eTiles + EB * 8 - 1) / (EB * 8);
    const int B0 = 1024;                                // edge0 blocks (256 thr)
    const int tpw0 = (eTiles + B0 * 4 - 1) / (B0 * 4);
    const int NB = 256;                                 // node blocks (512 thr)
    const int tpwN = (nTiles + NB * 8 - 1) / (NB * 8);
    const int nb = (N + 1023) / 1024;

    // ---- sort edges by dst ----
    hipMemsetAsync(cnt, 0, (size_t)N * 4, stream);
    hist_kernel<<<(E + 255) / 256, 256, 0, stream>>>(dst, cnt, E);
    scan1_kernel<<<nb, 256, 0, stream>>>(cnt, N, bSums);
    scan2_kernel<<<1, 256, 0, stream>>>(bSums, nb);
    scan3_kernel<<<nb, 256, 0, stream>>>(cnt, N, bSums);
    scatter_kernel<<<(E + 255) / 256, 256, 0, stream>>>(src, dst, wE, cnt, srcS, dstS, wS4, E);

    // ---- weight prep ----
    embW1_kernel<<<(NGT * 128 + 255) / 256, 256, 0, stream>>>(emb, W1_0, b1_0, eW1b, NGT);
    embW2_kernel<<<(NGT * 128 + 255) / 256, 256, 0, stream>>>(emb, W2_0, eW2, NGT);
    wprep_kernel<<<(128 * 160 + 255) / 256, 256, 0, stream>>>(W1_1, b1_1, W1T1, 131, 160);
    wprep_kernel<<<(128 * 160 + 255) / 256, 256, 0, stream>>>(W1_2, b1_2, W1T2, 131, 160);
    wprep_kernel<<<(128 * 128 + 255) / 256, 256, 0, stream>>>(W2_0 + (size_t)64 * 128, nullptr, W2T0, 128, 128);
    wprep_kernel<<<(128 * 256 + 255) / 256, 256, 0, stream>>>(W2_1, nullptr, W2T1, 256, 256);
    wprep_kernel<<<(128 * 256 + 255) / 256, 256, 0, stream>>>(W2_2, nullptr, W2T2, 256, 256);

    if (h16) {
        hipMemsetAsync(readout, 0, (size_t)(out_size - N * 128) * 4, stream);
        hipMemsetAsync(hN16, 0, (size_t)N * 128 * 2, stream);
        // layer 0
        edge0_kernel<true><<<B0, 256, 0, stream>>>(gate_type, eW1b, W1_0, srcS, dstS, wS4, hN, E, tpw0, eTiles);
        node_kernel<true, true, false><<<NB, 512, 0, stream>>>(nullptr, hN, W2T0, eW2, gate_type, n2g,
                                                               hBuf, nullptr, readout, N, tpwN, nTiles, 0);
        hipMemsetAsync(hN16, 0, (size_t)N * 128 * 2, stream);
        // layer 1
        edge_mfma_kernel<true><<<EB, 512, 0, stream>>>(hBuf, W1T1, srcS, dstS, wS4, hN, E, tpwE, eTiles);
        node_kernel<true, false, false><<<NB, 512, 0, stream>>>(hBuf, hN, W2T1, nullptr, nullptr, n2g,
                                                                hBuf, nullptr, readout, N, tpwN, nTiles, 128);
        hipMemsetAsync(hN16, 0, (size_t)N * 128 * 2, stream);
        // layer 2 (final fp32 h straight to d_out)
        edge_mfma_kernel<true><<<EB, 512, 0, stream>>>(hBuf, W1T2, srcS, dstS, wS4, hN, E, tpwE, eTiles);
        node_kernel<true, false, true><<<NB, 512, 0, stream>>>(hBuf, hN, W2T2, nullptr, nullptr, n2g,
                                                               nullptr, (float*)d_out, readout, N, tpwN, nTiles, 256);
    } else {
        hipMemsetAsync(d_out, 0, (size_t)out_size * 4, stream);
        // layer 0
        edge0_kernel<false><<<B0, 256, 0, stream>>>(gate_type, eW1b, W1_0, srcS, dstS, wS4, hN, E, tpw0, eTiles);
        node_kernel<false, true, false><<<NB, 512, 0, stream>>>(nullptr, hN, W2T0, eW2, gate_type, n2g,
                                                                hBuf, nullptr, readout, N, tpwN, nTiles, 0);
        hipMemsetAsync(d_out, 0, (size_t)N * 128 * 4, stream);
        // layer 1
        edge_mfma_kernel<false><<<EB, 512, 0, stream>>>(hBuf, W1T1, srcS, dstS, wS4, hN, E, tpwE, eTiles);
        node_kernel<false, false, false><<<NB, 512, 0, stream>>>(hBuf, hN, W2T1, nullptr, nullptr, n2g,
                                                                 hBuf, nullptr, readout, N, tpwN, nTiles, 128);
        hipMemsetAsync(d_out, 0, (size_t)N * 128 * 4, stream);
        // layer 2 (in-place over hN = d_out)
        edge_mfma_kernel<false><<<EB, 512, 0, stream>>>(hBuf, W1T2, srcS, dstS, wS4, hN, E, tpwE, eTiles);
        node_kernel<false, false, true><<<NB, 512, 0, stream>>>(hBuf, hN, W2T2, nullptr, nullptr, n2g,
                                                                nullptr, (float*)d_out, readout, N, tpwN, nTiles, 256);
    }
}

// Round 4
// 1099.221 us; speedup vs baseline: 1.3901x; 1.3901x over previous
//
#include <hip/hip_runtime.h>
#include <hip/hip_bf16.h>
#include <hip/hip_fp16.h>

typedef _Float16 half8 __attribute__((ext_vector_type(8)));
typedef _Float16 half4 __attribute__((ext_vector_type(4)));
typedef float floatx4 __attribute__((ext_vector_type(4)));

__device__ __forceinline__ _Float16 f2h(float f) { return (_Float16)f; }

// ---------------------------------------------------------------------------
// counting-sort of edges by dst
// ---------------------------------------------------------------------------
__global__ void hist_kernel(const int* __restrict__ dst, int* __restrict__ cnt, int E)
{
    int e = blockIdx.x * 256 + threadIdx.x;
    if (e < E) atomicAdd(&cnt[dst[e]], 1);
}

__global__ void scan1_kernel(int* __restrict__ data, int n, int* __restrict__ blockSums)
{
    __shared__ int sm[256];
    const int t = threadIdx.x;
    const int base = blockIdx.x * 1024 + t * 4;
    int v[4]; int s = 0;
#pragma unroll
    for (int i = 0; i < 4; ++i) { v[i] = (base + i < n) ? data[base + i] : 0; s += v[i]; }
    sm[t] = s; __syncthreads();
#pragma unroll
    for (int off = 1; off < 256; off <<= 1) {
        int y = (t >= off) ? sm[t - off] : 0;
        __syncthreads();
        if (t >= off) sm[t] += y;
        __syncthreads();
    }
    int excl = sm[t] - s;
    if (t == 255) blockSums[blockIdx.x] = sm[255];
    int run = excl;
#pragma unroll
    for (int i = 0; i < 4; ++i) {
        if (base + i < n) data[base + i] = run;
        run += v[i];
    }
}

__global__ void scan2_kernel(int* __restrict__ blockSums, int nb)
{
    __shared__ int sm[256];
    const int t = threadIdx.x;
    int s = (t < nb) ? blockSums[t] : 0;
    sm[t] = s; __syncthreads();
#pragma unroll
    for (int off = 1; off < 256; off <<= 1) {
        int y = (t >= off) ? sm[t - off] : 0;
        __syncthreads();
        if (t >= off) sm[t] += y;
        __syncthreads();
    }
    if (t < nb) blockSums[t] = sm[t] - s;
}

__global__ void scan3_kernel(int* __restrict__ data, int n, const int* __restrict__ blockSums)
{
    const int base = blockIdx.x * 1024 + threadIdx.x * 4;
    const int add = blockSums[blockIdx.x];
#pragma unroll
    for (int i = 0; i < 4; ++i)
        if (base + i < n) data[base + i] += add;
}

__global__ void scatter_kernel(const int* __restrict__ src, const int* __restrict__ dst,
                               const float* __restrict__ w, int* __restrict__ cursor,
                               int* __restrict__ srcS, int* __restrict__ dstS,
                               half4* __restrict__ wS4, int E)
{
    int e = blockIdx.x * 256 + threadIdx.x;
    if (e >= E) return;
    int d = dst[e];
    int p = atomicAdd(&cursor[d], 1);
    srcS[p] = src[e];
    dstS[p] = d;
    half4 q;
    q[0] = f2h(w[(size_t)e * 3 + 0]);
    q[1] = f2h(w[(size_t)e * 3 + 1]);
    q[2] = f2h(w[(size_t)e * 3 + 2]);
    q[3] = (_Float16)1.0f;             // constant-1 slot -> bias via MFMA (k=131)
    wS4[p] = q;
}

// ---------------------------------------------------------------------------
// weight prep: W [K,128] fp32 -> out [128,KP] f16, optional bias at col 131
// ---------------------------------------------------------------------------
__global__ void wprep_kernel(const float* __restrict__ W, const float* __restrict__ bias,
                             _Float16* __restrict__ out, int K, int KP)
{
    int idx = blockIdx.x * 256 + threadIdx.x;
    if (idx >= 128 * KP) return;
    int f = idx / KP, k = idx % KP;
    float v = 0.0f;
    if (k < K) v = W[(size_t)k * 128 + f];
    else if (bias != nullptr && k == 131) v = bias[f];
    out[idx] = f2h(v);
}

__global__ void embW1_kernel(const float* __restrict__ emb, const float* __restrict__ W1,
                             const float* __restrict__ b1, float* __restrict__ out, int NGT)
{
    int idx = blockIdx.x * 256 + threadIdx.x;
    if (idx >= NGT * 128) return;
    int g = idx >> 7, f = idx & 127;
    float s = b1[f];
    for (int k = 0; k < 64; ++k) s += emb[g * 64 + k] * W1[(size_t)k * 128 + f];
    out[idx] = s;
}

__global__ void embW2_kernel(const float* __restrict__ emb, const float* __restrict__ W2,
                             float* __restrict__ out, int NGT)
{
    int idx = blockIdx.x * 256 + threadIdx.x;
    if (idx >= NGT * 128) return;
    int g = idx >> 7, f = idx & 127;
    float s = 0.0f;
    for (int k = 0; k < 64; ++k) s += emb[g * 64 + k] * W2[(size_t)k * 128 + f];
    out[idx] = s;
}

// ---------------------------------------------------------------------------
// run-flush helper: one hN row (runD), cols jt*16+lRow, values runV[8]
// ---------------------------------------------------------------------------
template<bool H16>
__device__ __forceinline__ void flushRun(void* hNv, int runD, const float (&runV)[8],
                                         int lRow, int lane)
{
    if (H16) {
        __half* hN = (__half*)hNv;
#pragma unroll
        for (int jt = 0; jt < 8; ++jt) {
            float other = __shfl_xor(runV[jt], 1);          // all lanes execute
            if ((lane & 1) == 0 && (runV[jt] > 0.0f || other > 0.0f)) {
                __half2 v = __halves2half2(__float2half(runV[jt]), __float2half(other));
                unsafeAtomicAdd((__half2*)(hN + (size_t)runD * 128 + jt * 16 + lRow), v);
            }
        }
    } else {
        float* dp = (float*)hNv + (size_t)runD * 128 + lRow;
#pragma unroll
        for (int jt = 0; jt < 8; ++jt)
            if (runV[jt] > 0.0f) unsafeAtomicAdd(dp + jt * 16, runV[jt]);
    }
}

// ---------------------------------------------------------------------------
// edge layer 0 (no MFMA): t = relu(embW1b[gt[src]] + w@W1w); merged atomic add
// ---------------------------------------------------------------------------
template<bool H16>
__global__ void __launch_bounds__(256, 4)
edge0_kernel(const int* __restrict__ gt, const float* __restrict__ embW1b,
             const float* __restrict__ W1_0,
             const int* __restrict__ srcS, const int* __restrict__ dstS,
             const half4* __restrict__ wS4,
             void* __restrict__ hNv, int E, int tilesPerWave, int eTiles)
{
    const int tid  = threadIdx.x;
    const int lane = tid & 63;
    const int wv   = tid >> 6;
    const int lRow = lane & 15;
    const int lGrp = lane >> 4;

    float w1w[3][8];
#pragma unroll
    for (int c = 0; c < 3; ++c)
#pragma unroll
        for (int jt = 0; jt < 8; ++jt)
            w1w[c][jt] = W1_0[(size_t)(64 + c) * 128 + jt * 16 + lRow];

    const int wave = blockIdx.x * 4 + wv;
    const int t0 = wave * tilesPerWave;
    const int t1 = min(t0 + tilesPerWave, eTiles);

    for (int tile = t0; tile < t1; ++tile) {
        const int e0 = tile * 16;
        const int eb = e0 + lGrp * 4;
        int4 s4 = *(const int4*)(srcS + eb);   // padded past E
        int4 d4 = *(const int4*)(dstS + eb);
        const int s4a[4] = {s4.x, s4.y, s4.z, s4.w};
        const int d4a[4] = {d4.x, d4.y, d4.z, d4.w};

        int g4[4]; half4 q4[4];
#pragma unroll
        for (int r = 0; r < 4; ++r) {
            const bool v_ = (eb + r) < E;
            g4[r] = gt[v_ ? s4a[r] : 0];
            q4[r] = wS4[v_ ? (eb + r) : 0];
        }

        int runD; float runV[8];
        {
            const bool v_ = eb < E;
            runD = d4a[0];
            float w0 = (float)q4[0][0], w1 = (float)q4[0][1], w2 = (float)q4[0][2];
#pragma unroll
            for (int jt = 0; jt < 8; ++jt) {
                float m = embW1b[(size_t)g4[0] * 128 + jt * 16 + lRow]
                        + w0 * w1w[0][jt] + w1 * w1w[1][jt] + w2 * w1w[2][jt];
                runV[jt] = v_ ? fmaxf(m, 0.0f) : 0.0f;
            }
        }
#pragma unroll
        for (int r = 1; r < 4; ++r) {
            const bool v_ = (eb + r) < E;
            const int d_ = d4a[r];
            float w0 = (float)q4[r][0], w1 = (float)q4[r][1], w2 = (float)q4[r][2];
            float vr[8];
#pragma unroll
            for (int jt = 0; jt < 8; ++jt) {
                float m = embW1b[(size_t)g4[r] * 128 + jt * 16 + lRow]
                        + w0 * w1w[0][jt] + w1 * w1w[1][jt] + w2 * w1w[2][jt];
                vr[jt] = v_ ? fmaxf(m, 0.0f) : 0.0f;
            }
            if (d_ == runD) {
#pragma unroll
                for (int jt = 0; jt < 8; ++jt) runV[jt] += vr[jt];
            } else {
                flushRun<H16>(hNv, runD, runV, lRow, lane);
                runD = d_;
#pragma unroll
                for (int jt = 0; jt < 8; ++jt) runV[jt] = vr[jt];
            }
        }
        flushRun<H16>(hNv, runD, runV, lRow, lane);
    }
}

// ---------------------------------------------------------------------------
// edge layers 1,2 (MFMA): round-2 structure + paired-tile MLP
// ---------------------------------------------------------------------------
template<bool H16>
__global__ void __launch_bounds__(256, 3)
edge_mfma_kernel(const _Float16* __restrict__ hA,   // [N,128]
                 const _Float16* __restrict__ W1T,  // [128,160]
                 const int* __restrict__ srcS, const int* __restrict__ dstS,
                 const half4* __restrict__ wS4,
                 void* __restrict__ hNv, int E, int tilesPerWave, int eTiles)
{
    constexpr int KPAD = 160, KC = 5, SPR = 20, LDSK = 192;
    __shared__ __align__(16) _Float16 lds[128 * LDSK];

    const int tid = threadIdx.x;
    for (int s = tid; s < 128 * SPR; s += 256) {
        const int row = s / SPR, seg = s % SPR;
        half8 v = *(const half8*)(W1T + (size_t)row * KPAD + seg * 8);
        *(half8*)(&lds[row * LDSK + ((seg ^ (row & 7)) * 8)]) = v;
    }
    __syncthreads();

    const int lane = tid & 63;
    const int wv   = tid >> 6;
    const int lRow = lane & 15;
    const int lGrp = lane >> 4;
    const int wave = blockIdx.x * 4 + wv;
    const int t0 = wave * tilesPerWave;
    const int t1 = min(t0 + tilesPerWave, eTiles);

    auto loadA = [&](int tile, half8 (&F)[5]) {
        const int eA = min(tile * 16 + lRow, E - 1);
        const int s_ = srcS[eA];
        const half4 q = wS4[eA];
#pragma unroll
        for (int kc = 0; kc < 4; ++kc)
            F[kc] = *(const half8*)(hA + (size_t)s_ * 128 + kc * 32 + lGrp * 8);
        half8 aw = {};
        if (lGrp == 0) { aw[0] = q[0]; aw[1] = q[1]; aw[2] = q[2]; aw[3] = q[3]; }
        F[4] = aw;
    };
    auto compute = [&](const half8 (&F)[5], int tile) {
        floatx4 acc[8] = {};
#pragma unroll
        for (int jt = 0; jt < 8; ++jt) {
            const int rb = (jt * 16 + lRow) * LDSK;
            const int sw = (jt * 16 + lRow) & 7;
#pragma unroll
            for (int kc = 0; kc < KC; ++kc) {
                half8 b = *(const half8*)(&lds[rb + (((kc * 4 + lGrp) ^ sw) * 8)]);
                acc[jt] = __builtin_amdgcn_mfma_f32_16x16x32_f16(F[kc], b, acc[jt], 0, 0, 0);
            }
        }
        const int eb = tile * 16 + lGrp * 4;
        const int4 d4 = *(const int4*)(dstS + eb);     // padded past E
        const int d4a[4] = {d4.x, d4.y, d4.z, d4.w};
        int runD; float runV[8];
        {
            const bool v_ = eb < E;
            runD = d4a[0];
#pragma unroll
            for (int jt = 0; jt < 8; ++jt) runV[jt] = v_ ? fmaxf(acc[jt][0], 0.0f) : 0.0f;
        }
#pragma unroll
        for (int r = 1; r < 4; ++r) {
            const bool v_ = (eb + r) < E;
            const int d_ = d4a[r];
            if (d_ == runD) {
#pragma unroll
                for (int jt = 0; jt < 8; ++jt)
                    runV[jt] += v_ ? fmaxf(acc[jt][r], 0.0f) : 0.0f;
            } else {
                flushRun<H16>(hNv, runD, runV, lRow, lane);
                runD = d_;
#pragma unroll
                for (int jt = 0; jt < 8; ++jt)
                    runV[jt] = v_ ? fmaxf(acc[jt][r], 0.0f) : 0.0f;
            }
        }
        flushRun<H16>(hNv, runD, runV, lRow, lane);
    };

    for (int t = t0; t < t1; t += 2) {
        const bool hasB = (t + 1 < t1);
        half8 FA[5], FB[5];
        loadA(t, FA);
        loadA(hasB ? t + 1 : t, FB);     // both gathers in flight before MFMAs
        compute(FA, t);
        if (hasB) compute(FB, t + 1);
    }
}

// ---------------------------------------------------------------------------
// node kernel: h = normalize(relu([h,]hN @ W2 [+ embW2[gt]])); readout
// ---------------------------------------------------------------------------
template<bool H16, bool L0, bool LAST>
__global__ void __launch_bounds__(256, 2)
node_kernel(const _Float16* __restrict__ hA,    // [N,128] (unused if L0)
            const void* __restrict__ hNv,       // [N,128] f16 or f32
            const _Float16* __restrict__ W2T,   // [128,K2]
            const float* __restrict__ embW2,    // [30,128] (L0 only)
            const int* __restrict__ gt,         // (L0 only)
            const int* __restrict__ n2g,
            _Float16* __restrict__ hOut,        // if !LAST
            float* __restrict__ fOut,           // if LAST
            float* __restrict__ readout,
            int N, int tilesPerWave, int nTiles, int layerOff)
{
    constexpr int K2  = L0 ? 128 : 256;
    constexpr int KCA = L0 ? 0 : 4;
    constexpr int KC  = K2 / 32;
    constexpr int SPR = K2 / 8;
    __shared__ __align__(16) _Float16 lds[128 * K2];

    const int tid = threadIdx.x;
    for (int s = tid; s < 128 * SPR; s += 256) {
        const int row = s / SPR, seg = s % SPR;
        half8 v = *(const half8*)(W2T + (size_t)row * K2 + seg * 8);
        *(half8*)(&lds[row * K2 + ((seg ^ (row & 7)) * 8)]) = v;
    }
    __syncthreads();

    const int lane = tid & 63;
    const int wv   = tid >> 6;
    const int lRow = lane & 15;
    const int lGrp = lane >> 4;
    const int wave = blockIdx.x * 4 + wv;
    const int t0 = wave * tilesPerWave;
    const int t1 = min(t0 + tilesPerWave, nTiles);
    if (t0 >= t1) return;

    int gCur = -1; float racc[8];
#pragma unroll
    for (int jt = 0; jt < 8; ++jt) racc[jt] = 0.0f;

    for (int tile = t0; tile < t1; ++tile) {
        const int i0 = tile * 16;
        const int iA = min(i0 + lRow, N - 1);

        half8 afrag[KC];
#pragma unroll
        for (int kc = 0; kc < KCA; ++kc)
            afrag[kc] = *(const half8*)(hA + (size_t)iA * 128 + kc * 32 + lGrp * 8);
        if (H16) {
            const _Float16* hN = (const _Float16*)hNv;
#pragma unroll
            for (int kc = KCA; kc < KC; ++kc)
                afrag[kc] = *(const half8*)(hN + (size_t)iA * 128 + (kc - KCA) * 32 + lGrp * 8);
        } else {
            const float* hN = (const float*)hNv;
#pragma unroll
            for (int kc = KCA; kc < KC; ++kc) {
                const float* p = hN + (size_t)iA * 128 + (kc - KCA) * 32 + lGrp * 8;
                floatx4 f0 = *(const floatx4*)(p);
                floatx4 f1 = *(const floatx4*)(p + 4);
                half8 a;
#pragma unroll
                for (int i = 0; i < 4; ++i) { a[i] = f2h(f0[i]); a[i + 4] = f2h(f1[i]); }
                afrag[kc] = a;
            }
        }

        floatx4 acc[8] = {};
#pragma unroll
        for (int jt = 0; jt < 8; ++jt) {
            const int rb = (jt * 16 + lRow) * K2;
            const int sw = (jt * 16 + lRow) & 7;
#pragma unroll
            for (int kc = 0; kc < KC; ++kc) {
                half8 b = *(const half8*)(&lds[rb + (((kc * 4 + lGrp) ^ sw) * 8)]);
                acc[jt] = __builtin_amdgcn_mfma_f32_16x16x32_f16(afrag[kc], b, acc[jt], 0, 0, 0);
            }
        }

        if (L0) {
#pragma unroll
            for (int r = 0; r < 4; ++r) {
                const int i = min(i0 + lGrp * 4 + r, N - 1);
                const int g_t = gt[i];
#pragma unroll
                for (int jt = 0; jt < 8; ++jt)
                    acc[jt][r] += embW2[(size_t)g_t * 128 + jt * 16 + lRow];
            }
        }

        float scl[4];
#pragma unroll
        for (int r = 0; r < 4; ++r) {
            float s = 0.f;
#pragma unroll
            for (int jt = 0; jt < 8; ++jt) {
                float v = fmaxf(acc[jt][r], 0.0f);
                s += v * v;
            }
#pragma unroll
            for (int m = 1; m <= 8; m <<= 1) s += __shfl_xor(s, m);
            scl[r] = 1.0f / fmaxf(sqrtf(s), 1e-12f);
        }

#pragma unroll
        for (int r = 0; r < 4; ++r) {
            const int i = i0 + lGrp * 4 + r;
            if (i < N) {
#pragma unroll
                for (int jt = 0; jt < 8; ++jt) {
                    float v = fmaxf(acc[jt][r], 0.0f) * scl[r];
                    if (LAST) fOut[(size_t)i * 128 + jt * 16 + lRow] = v;
                    else      hOut[(size_t)i * 128 + jt * 16 + lRow] = f2h(v);
                }
            }
        }

        // readout (sorted n2g): accumulate across same-graph tiles in registers
        const int gFirst = n2g[min(i0, N - 1)];
        const int gLast  = n2g[min(i0 + 15, N - 1)];
        if (gFirst == gLast && i0 + 15 < N) {
            if (gFirst != gCur) {
                if (gCur >= 0 && lane < 16) {
#pragma unroll
                    for (int jt = 0; jt < 8; ++jt)
                        unsafeAtomicAdd(&readout[(size_t)gCur * 384 + layerOff + jt * 16 + lane], racc[jt]);
                }
                gCur = gFirst;
#pragma unroll
                for (int jt = 0; jt < 8; ++jt) racc[jt] = 0.0f;
            }
#pragma unroll
            for (int jt = 0; jt < 8; ++jt) {
                float t = 0.f;
#pragma unroll
                for (int r = 0; r < 4; ++r) t += fmaxf(acc[jt][r], 0.0f) * scl[r];
                t += __shfl_xor(t, 16);
                t += __shfl_xor(t, 32);
                racc[jt] += t;
            }
        } else {
            if (gCur >= 0 && lane < 16) {
#pragma unroll
                for (int jt = 0; jt < 8; ++jt)
                    unsafeAtomicAdd(&readout[(size_t)gCur * 384 + layerOff + jt * 16 + lane], racc[jt]);
            }
            gCur = -1;
#pragma unroll
            for (int jt = 0; jt < 8; ++jt) racc[jt] = 0.0f;
#pragma unroll
            for (int r = 0; r < 4; ++r) {
                const int i = i0 + lGrp * 4 + r;
                if (i < N) {
                    const int g = n2g[i];
#pragma unroll
                    for (int jt = 0; jt < 8; ++jt) {
                        float v = fmaxf(acc[jt][r], 0.0f) * scl[r];
                        unsafeAtomicAdd(&readout[(size_t)g * 384 + layerOff + jt * 16 + lRow], v);
                    }
                }
            }
        }
    }
    if (gCur >= 0 && lane < 16) {
#pragma unroll
        for (int jt = 0; jt < 8; ++jt)
            unsafeAtomicAdd(&readout[(size_t)gCur * 384 + layerOff + jt * 16 + lane], racc[jt]);
    }
}

// ---------------------------------------------------------------------------
extern "C" void kernel_launch(void* const* d_in, const int* in_sizes, int n_in,
                              void* d_out, int out_size, void* d_ws, size_t ws_size,
                              hipStream_t stream)
{
    const int*   gate_type = (const int*)d_in[0];
    const int*   src  = (const int*)d_in[1];
    const int*   dst  = (const int*)d_in[2];
    const float* wE   = (const float*)d_in[3];
    const int*   n2g  = (const int*)d_in[4];
    const float* emb  = (const float*)d_in[5];
    const float* W1_0 = (const float*)d_in[6];
    const float* b1_0 = (const float*)d_in[7];
    const float* W2_0 = (const float*)d_in[8];
    const float* W1_1 = (const float*)d_in[9];
    const float* b1_1 = (const float*)d_in[10];
    const float* W2_1 = (const float*)d_in[11];
    const float* W1_2 = (const float*)d_in[12];
    const float* b1_2 = (const float*)d_in[13];
    const float* W2_2 = (const float*)d_in[14];

    const int N = in_sizes[0];
    const int E = in_sizes[1];
    const int NGT = in_sizes[5] / 64;

    char* ws = (char*)d_ws;
    size_t off = 0;
    auto alloc = [&](size_t bytes) { void* p = ws + off; off = (off + bytes + 255) & ~255ULL; return p; };
    _Float16* hBuf  = (_Float16*)alloc((size_t)N * 128 * 2);
    int*      srcS  = (int*)alloc(((size_t)E + 16) * 4);
    int*      dstS  = (int*)alloc(((size_t)E + 16) * 4);
    half4*    wS4   = (half4*)alloc(((size_t)E + 16) * 8);
    int*      cnt   = (int*)alloc((size_t)N * 4);
    int*      bSums = (int*)alloc(256 * 4);
    _Float16* W1T1  = (_Float16*)alloc((size_t)128 * 160 * 2);
    _Float16* W1T2  = (_Float16*)alloc((size_t)128 * 160 * 2);
    _Float16* W2T0  = (_Float16*)alloc((size_t)128 * 128 * 2);
    _Float16* W2T1  = (_Float16*)alloc((size_t)128 * 256 * 2);
    _Float16* W2T2  = (_Float16*)alloc((size_t)128 * 256 * 2);
    float*    eW1b  = (float*)alloc((size_t)NGT * 128 * 4);
    float*    eW2   = (float*)alloc((size_t)NGT * 128 * 4);
    size_t hn16_off = off;
    const bool h16 = (ws_size >= hn16_off + (size_t)N * 128 * 2 + 256);
    _Float16* hN16 = (_Float16*)alloc((size_t)N * 128 * 2);   // only used if h16

    float* readout = (float*)d_out + (size_t)N * 128;  // [G,384]
    void*  hN      = h16 ? (void*)hN16 : (void*)d_out; // fp32 fallback: d_out

    const int eTiles = (E + 15) / 16;
    const int nTiles = (N + 15) / 16;
    const int EB = 768;                                 // edge blocks (256 thr)
    const int tpwE = (eTiles + EB * 4 - 1) / (EB * 4);
    const int B0 = 1024;                                // edge0 blocks (256 thr)
    const int tpw0 = (eTiles + B0 * 4 - 1) / (B0 * 4);
    const int NB = 512;                                 // node blocks (256 thr)
    const int tpwN = (nTiles + NB * 4 - 1) / (NB * 4);
    const int nb = (N + 1023) / 1024;

    // ---- sort edges by dst ----
    hipMemsetAsync(cnt, 0, (size_t)N * 4, stream);
    hist_kernel<<<(E + 255) / 256, 256, 0, stream>>>(dst, cnt, E);
    scan1_kernel<<<nb, 256, 0, stream>>>(cnt, N, bSums);
    scan2_kernel<<<1, 256, 0, stream>>>(bSums, nb);
    scan3_kernel<<<nb, 256, 0, stream>>>(cnt, N, bSums);
    scatter_kernel<<<(E + 255) / 256, 256, 0, stream>>>(src, dst, wE, cnt, srcS, dstS, wS4, E);

    // ---- weight prep ----
    embW1_kernel<<<(NGT * 128 + 255) / 256, 256, 0, stream>>>(emb, W1_0, b1_0, eW1b, NGT);
    embW2_kernel<<<(NGT * 128 + 255) / 256, 256, 0, stream>>>(emb, W2_0, eW2, NGT);
    wprep_kernel<<<(128 * 160 + 255) / 256, 256, 0, stream>>>(W1_1, b1_1, W1T1, 131, 160);
    wprep_kernel<<<(128 * 160 + 255) / 256, 256, 0, stream>>>(W1_2, b1_2, W1T2, 131, 160);
    wprep_kernel<<<(128 * 128 + 255) / 256, 256, 0, stream>>>(W2_0 + (size_t)64 * 128, nullptr, W2T0, 128, 128);
    wprep_kernel<<<(128 * 256 + 255) / 256, 256, 0, stream>>>(W2_1, nullptr, W2T1, 256, 256);
    wprep_kernel<<<(128 * 256 + 255) / 256, 256, 0, stream>>>(W2_2, nullptr, W2T2, 256, 256);

    if (h16) {
        hipMemsetAsync(readout, 0, (size_t)(out_size - N * 128) * 4, stream);
        hipMemsetAsync(hN16, 0, (size_t)N * 128 * 2, stream);
        // layer 0
        edge0_kernel<true><<<B0, 256, 0, stream>>>(gate_type, eW1b, W1_0, srcS, dstS, wS4, hN, E, tpw0, eTiles);
        node_kernel<true, true, false><<<NB, 256, 0, stream>>>(nullptr, hN, W2T0, eW2, gate_type, n2g,
                                                               hBuf, nullptr, readout, N, tpwN, nTiles, 0);
        hipMemsetAsync(hN16, 0, (size_t)N * 128 * 2, stream);
        // layer 1
        edge_mfma_kernel<true><<<EB, 256, 0, stream>>>(hBuf, W1T1, srcS, dstS, wS4, hN, E, tpwE, eTiles);
        node_kernel<true, false, false><<<NB, 256, 0, stream>>>(hBuf, hN, W2T1, nullptr, nullptr, n2g,
                                                                hBuf, nullptr, readout, N, tpwN, nTiles, 128);
        hipMemsetAsync(hN16, 0, (size_t)N * 128 * 2, stream);
        // layer 2 (final fp32 h straight to d_out)
        edge_mfma_kernel<true><<<EB, 256, 0, stream>>>(hBuf, W1T2, srcS, dstS, wS4, hN, E, tpwE, eTiles);
        node_kernel<true, false, true><<<NB, 256, 0, stream>>>(hBuf, hN, W2T2, nullptr, nullptr, n2g,
                                                               nullptr, (float*)d_out, readout, N, tpwN, nTiles, 256);
    } else {
        hipMemsetAsync(d_out, 0, (size_t)out_size * 4, stream);
        // layer 0
        edge0_kernel<false><<<B0, 256, 0, stream>>>(gate_type, eW1b, W1_0, srcS, dstS, wS4, hN, E, tpw0, eTiles);
        node_kernel<false, true, false><<<NB, 256, 0, stream>>>(nullptr, hN, W2T0, eW2, gate_type, n2g,
                                                                hBuf, nullptr, readout, N, tpwN, nTiles, 0);
        hipMemsetAsync(d_out, 0, (size_t)N * 128 * 4, stream);
        // layer 1
        edge_mfma_kernel<false><<<EB, 256, 0, stream>>>(hBuf, W1T1, srcS, dstS, wS4, hN, E, tpwE, eTiles);
        node_kernel<false, false, false><<<NB, 256, 0, stream>>>(hBuf, hN, W2T1, nullptr, nullptr, n2g,
                                                                 hBuf, nullptr, readout, N, tpwN, nTiles, 128);
        hipMemsetAsync(d_out, 0, (size_t)N * 128 * 4, stream);
        // layer 2 (in-place over hN = d_out)
        edge_mfma_kernel<false><<<EB, 256, 0, stream>>>(hBuf, W1T2, srcS, dstS, wS4, hN, E, tpwE, eTiles);
        node_kernel<false, false, true><<<NB, 256, 0, stream>>>(hBuf, hN, W2T2, nullptr, nullptr, n2g,
                                                                nullptr, (float*)d_out, readout, N, tpwN, nTiles, 256);
    }
}

// Round 5
// 1019.988 us; speedup vs baseline: 1.4981x; 1.0777x over previous
//
#include <hip/hip_runtime.h>
#include <hip/hip_bf16.h>
#include <hip/hip_fp16.h>

typedef _Float16 half8 __attribute__((ext_vector_type(8)));
typedef _Float16 half4 __attribute__((ext_vector_type(4)));
typedef float floatx4 __attribute__((ext_vector_type(4)));

__device__ __forceinline__ _Float16 f2h(float f) { return (_Float16)f; }

// ---------------------------------------------------------------------------
// dummy-fill the padded edge arrays: src=N (zero row), g=NGT (zero emb row),
// dst=N (skip marker). wS4 is zeroed by memset.
// ---------------------------------------------------------------------------
__global__ void fill_dummy_kernel(int* __restrict__ srcS, int* __restrict__ dstS,
                                  int cap, int N, int NGT)
{
    int i = blockIdx.x * 256 + threadIdx.x;
    if (i < cap) { srcS[i] = N | (NGT << 24); dstS[i] = N; }
}

__global__ void hist_kernel(const int* __restrict__ dst, int* __restrict__ cnt, int E)
{
    int e = blockIdx.x * 256 + threadIdx.x;
    if (e < E) atomicAdd(&cnt[dst[e]], 1);
}

// exclusive scan of per-node counts PADDED to multiple of 4 -> offP
__global__ void scan1p_kernel(const int* __restrict__ cnt, int* __restrict__ offP,
                              int n, int* __restrict__ blockSums)
{
    __shared__ int sm[256];
    const int t = threadIdx.x;
    const int base = blockIdx.x * 1024 + t * 4;
    int v[4]; int s = 0;
#pragma unroll
    for (int i = 0; i < 4; ++i) {
        v[i] = (base + i < n) ? ((cnt[base + i] + 3) & ~3) : 0;
        s += v[i];
    }
    sm[t] = s; __syncthreads();
#pragma unroll
    for (int off = 1; off < 256; off <<= 1) {
        int y = (t >= off) ? sm[t - off] : 0;
        __syncthreads();
        if (t >= off) sm[t] += y;
        __syncthreads();
    }
    int excl = sm[t] - s;
    if (t == 255) blockSums[blockIdx.x] = sm[255];
    int run = excl;
#pragma unroll
    for (int i = 0; i < 4; ++i) {
        if (base + i < n) offP[base + i] = run;
        run += v[i];
    }
}

__global__ void scan2_kernel(int* __restrict__ blockSums, int nb)
{
    __shared__ int sm[256];
    const int t = threadIdx.x;
    int s = (t < nb) ? blockSums[t] : 0;
    sm[t] = s; __syncthreads();
#pragma unroll
    for (int off = 1; off < 256; off <<= 1) {
        int y = (t >= off) ? sm[t - off] : 0;
        __syncthreads();
        if (t >= off) sm[t] += y;
        __syncthreads();
    }
    if (t < nb) blockSums[t] = sm[t] - s;
}

__global__ void scan3_kernel(int* __restrict__ offP, int n, const int* __restrict__ blockSums)
{
    const int base = blockIdx.x * 1024 + threadIdx.x * 4;
    const int add = blockSums[blockIdx.x];
#pragma unroll
    for (int i = 0; i < 4; ++i)
        if (base + i < n) offP[base + i] += add;
}

__global__ void scatter_kernel(const int* __restrict__ src, const int* __restrict__ dst,
                               const float* __restrict__ w, const int* __restrict__ gt,
                               const int* __restrict__ offP, int* __restrict__ cur,
                               int* __restrict__ srcS, int* __restrict__ dstS,
                               half4* __restrict__ wS4, int E)
{
    int e = blockIdx.x * 256 + threadIdx.x;
    if (e >= E) return;
    int d = dst[e];
    int p = offP[d] + atomicAdd(&cur[d], 1);
    int s = src[e];
    srcS[p] = s | (gt[s] << 24);
    dstS[p] = d;
    half4 q;
    q[0] = f2h(w[(size_t)e * 3 + 0]);
    q[1] = f2h(w[(size_t)e * 3 + 1]);
    q[2] = f2h(w[(size_t)e * 3 + 2]);
    q[3] = (_Float16)1.0f;             // bias slot (k=131); pads stay 0 -> no bias
    wS4[p] = q;
}

// ---------------------------------------------------------------------------
// weight prep: W [K,128] fp32 -> out [128,KP] f16, optional bias at col 131
// ---------------------------------------------------------------------------
__global__ void wprep_kernel(const float* __restrict__ W, const float* __restrict__ bias,
                             _Float16* __restrict__ out, int K, int KP)
{
    int idx = blockIdx.x * 256 + threadIdx.x;
    if (idx >= 128 * KP) return;
    int f = idx / KP, k = idx % KP;
    float v = 0.0f;
    if (k < K) v = W[(size_t)k * 128 + f];
    else if (bias != nullptr && k == 131) v = bias[f];
    out[idx] = f2h(v);
}

// embW1b[g][f] = b1_0[f] + emb[g]@W1_0[:64]; row NGT = zeros (pad edges)
__global__ void embW1_kernel(const float* __restrict__ emb, const float* __restrict__ W1,
                             const float* __restrict__ b1, float* __restrict__ out, int NGT)
{
    int idx = blockIdx.x * 256 + threadIdx.x;
    if (idx >= (NGT + 1) * 128) return;
    int g = idx >> 7, f = idx & 127;
    float s = 0.0f;
    if (g < NGT) {
        s = b1[f];
        for (int k = 0; k < 64; ++k) s += emb[g * 64 + k] * W1[(size_t)k * 128 + f];
    }
    out[idx] = s;
}

__global__ void embW2_kernel(const float* __restrict__ emb, const float* __restrict__ W2,
                             float* __restrict__ out, int NGT)
{
    int idx = blockIdx.x * 256 + threadIdx.x;
    if (idx >= NGT * 128) return;
    int g = idx >> 7, f = idx & 127;
    float s = 0.0f;
    for (int k = 0; k < 64; ++k) s += emb[g * 64 + k] * W2[(size_t)k * 128 + f];
    out[idx] = s;
}

// ---------------------------------------------------------------------------
// group output: plain store if dst owned by one group, else atomic accumulate
// ---------------------------------------------------------------------------
template<bool H16>
__device__ __forceinline__ void outGroup(void* hNv, int dG, bool multi,
                                         const float (&v)[8], int lRow, int lane)
{
    if (H16) {
        __half* hN = (__half*)hNv;
#pragma unroll
        for (int jt = 0; jt < 8; ++jt) {
            float other = __shfl_xor(v[jt], 1);
            if ((lane & 1) == 0) {
                __half2 p = __halves2half2(__float2half(v[jt]), __float2half(other));
                __half2* addr = (__half2*)(hN + (size_t)dG * 128 + jt * 16 + lRow);
                if (multi) unsafeAtomicAdd(addr, p);
                else       *addr = p;
            }
        }
    } else {
        float* hN = (float*)hNv;
#pragma unroll
        for (int jt = 0; jt < 8; ++jt) {
            float* addr = hN + (size_t)dG * 128 + jt * 16 + lRow;
            if (multi) unsafeAtomicAdd(addr, v[jt]);
            else       *addr = v[jt];
        }
    }
}

// ---------------------------------------------------------------------------
// edge layer 0 (no MFMA): per group sum of relu(embW1b[g] + w@W1w) -> store
// ---------------------------------------------------------------------------
template<bool H16>
__global__ void __launch_bounds__(256, 4)
edge0_kernel(const float* __restrict__ embW1b, const float* __restrict__ W1_0,
             const int* __restrict__ srcS, const int* __restrict__ dstS,
             const half4* __restrict__ wS4,
             void* __restrict__ hNv, int N, int tilesPerWave, int eTiles4)
{
    const int tid  = threadIdx.x;
    const int lane = tid & 63;
    const int wv   = tid >> 6;
    const int lRow = lane & 15;
    const int lGrp = lane >> 4;

    float w1w[3][8];
#pragma unroll
    for (int c = 0; c < 3; ++c)
#pragma unroll
        for (int jt = 0; jt < 8; ++jt)
            w1w[c][jt] = W1_0[(size_t)(64 + c) * 128 + jt * 16 + lRow];

    const int wave = blockIdx.x * 4 + wv;
    const int t0 = wave * tilesPerWave;
    const int t1 = min(t0 + tilesPerWave, eTiles4);

    for (int tile = t0; tile < t1; ++tile) {
        const int e0 = tile * 16;
        if (dstS[e0] >= N) continue;           // all-dummy tail tile
        const int eb = e0 + lGrp * 4;
        const int dG = dstS[eb];
        int4 s4 = *(const int4*)(srcS + eb);
        const int sArr[4] = {s4.x, s4.y, s4.z, s4.w};

        float sum[8];
#pragma unroll
        for (int jt = 0; jt < 8; ++jt) sum[jt] = 0.0f;

#pragma unroll
        for (int r = 0; r < 4; ++r) {
            const int g = sArr[r] >> 24;       // NGT for pads -> zero row
            const half4 q = wS4[eb + r];
            const float w0 = (float)q[0], w1 = (float)q[1], w2 = (float)q[2];
            const float* e1 = embW1b + (size_t)g * 128;
#pragma unroll
            for (int jt = 0; jt < 8; ++jt) {
                float m = e1[jt * 16 + lRow]
                        + w0 * w1w[0][jt] + w1 * w1w[1][jt] + w2 * w1w[2][jt];
                sum[jt] += fmaxf(m, 0.0f);
            }
        }
        if (dG < N) {
            bool multi = ((eb >= 4 && dstS[eb - 4] == dG) || dstS[eb + 4] == dG);
            outGroup<H16>(hNv, dG, multi, sum, lRow, lane);
        }
    }
}

// ---------------------------------------------------------------------------
// edge layers 1,2 (MFMA): single-dst groups -> reg sum -> store/atomic
// LDS 34.8KB: 16-seg swizzled main + compact w-chunk + zero block -> 4 blk/CU
// ---------------------------------------------------------------------------
template<bool H16>
__global__ void __launch_bounds__(256, 4)
edge_mfma_kernel(const _Float16* __restrict__ hA,   // [(N+1),128], row N = 0
                 const _Float16* __restrict__ W1T,  // [128,136] (w rows + bias@131)
                 const int* __restrict__ srcS, const int* __restrict__ dstS,
                 const half4* __restrict__ wS4,
                 void* __restrict__ hNv, int N, int tilesPerWave, int eTiles4)
{
    constexpr int WOFF = 128 * 128;
    constexpr int ZOFF = 128 * 128 + 128 * 8;
    __shared__ __align__(16) _Float16 lds[128 * 128 + 128 * 8 + 8];

    const int tid = threadIdx.x;
    for (int s = tid; s < 128 * 17; s += 256) {
        const int row = s / 17, seg = s % 17;
        half8 v = *(const half8*)(W1T + (size_t)row * 136 + seg * 8);
        if (seg < 16) *(half8*)(&lds[row * 128 + ((seg ^ (row & 7)) * 8)]) = v;
        else          *(half8*)(&lds[WOFF + row * 8]) = v;
    }
    if (tid < 8) lds[ZOFF + tid] = (_Float16)0.0f;
    __syncthreads();

    const int lane = tid & 63;
    const int wv   = tid >> 6;
    const int lRow = lane & 15;
    const int lGrp = lane >> 4;
    const int wave = blockIdx.x * 4 + wv;
    const int t0 = wave * tilesPerWave;
    const int t1 = min(t0 + tilesPerWave, eTiles4);

    for (int tile = t0; tile < t1; ++tile) {
        const int e0 = tile * 16;
        if (dstS[e0] >= N) continue;           // all-dummy tail tile
        const int eA = e0 + lRow;
        const int s_ = srcS[eA] & 0xFFFFFF;    // pads -> row N (zeros)
        const half4 q = wS4[eA];

        half8 F[5];
#pragma unroll
        for (int kc = 0; kc < 4; ++kc)
            F[kc] = *(const half8*)(hA + (size_t)s_ * 128 + kc * 32 + lGrp * 8);
        {
            half8 aw = {};
            if (lGrp == 0) { aw[0] = q[0]; aw[1] = q[1]; aw[2] = q[2]; aw[3] = q[3]; }
            F[4] = aw;
        }

        floatx4 acc[8] = {};
#pragma unroll
        for (int jt = 0; jt < 8; ++jt) {
            const int row = jt * 16 + lRow;
#pragma unroll
            for (int kc = 0; kc < 4; ++kc) {
                half8 b = *(const half8*)(&lds[row * 128 + (((kc * 4 + lGrp) ^ (row & 7)) * 8)]);
                acc[jt] = __builtin_amdgcn_mfma_f32_16x16x32_f16(F[kc], b, acc[jt], 0, 0, 0);
            }
            half8 bw = *(const half8*)(&lds[lGrp == 0 ? (WOFF + row * 8) : ZOFF]);
            acc[jt] = __builtin_amdgcn_mfma_f32_16x16x32_f16(F[4], bw, acc[jt], 0, 0, 0);
        }

        const int eb = e0 + lGrp * 4;
        const int dG = dstS[eb];
        if (dG < N) {
            float v[8];
#pragma unroll
            for (int jt = 0; jt < 8; ++jt)
                v[jt] = fmaxf(acc[jt][0], 0.f) + fmaxf(acc[jt][1], 0.f)
                      + fmaxf(acc[jt][2], 0.f) + fmaxf(acc[jt][3], 0.f);
            bool multi = ((eb >= 4 && dstS[eb - 4] == dG) || dstS[eb + 4] == dG);
            outGroup<H16>(hNv, dG, multi, v, lRow, lane);
        }
    }
}

// ---------------------------------------------------------------------------
// node kernel: h = normalize(relu([h,]hN @ W2 [+ embW2[gt]])); readout
// 512 threads, (512,2) -> 2 blocks/CU, 16 waves/CU, VGPR cap 128
// ---------------------------------------------------------------------------
template<bool H16, bool L0, bool LAST>
__global__ void __launch_bounds__(512, 2)
node_kernel(const _Float16* __restrict__ hA,    // [N,128] (unused if L0)
            const void* __restrict__ hNv,       // [N,128] f16 or f32
            const _Float16* __restrict__ W2T,   // [128,K2]
            const float* __restrict__ embW2,    // [30,128] (L0 only)
            const int* __restrict__ gt,         // (L0 only)
            const int* __restrict__ n2g,
            _Float16* __restrict__ hOut,        // if !LAST
            float* __restrict__ fOut,           // if LAST
            float* __restrict__ readout,
            int N, int tilesPerWave, int nTiles, int layerOff)
{
    constexpr int K2  = L0 ? 128 : 256;
    constexpr int KCA = L0 ? 0 : 4;
    constexpr int KC  = K2 / 32;
    constexpr int SPR = K2 / 8;
    __shared__ __align__(16) _Float16 lds[128 * K2];

    const int tid = threadIdx.x;
    for (int s = tid; s < 128 * SPR; s += 512) {
        const int row = s / SPR, seg = s % SPR;
        half8 v = *(const half8*)(W2T + (size_t)row * K2 + seg * 8);
        *(half8*)(&lds[row * K2 + ((seg ^ (row & 7)) * 8)]) = v;
    }
    __syncthreads();

    const int lane = tid & 63;
    const int wv   = tid >> 6;
    const int lRow = lane & 15;
    const int lGrp = lane >> 4;
    const int wave = blockIdx.x * 8 + wv;
    const int t0 = wave * tilesPerWave;
    const int t1 = min(t0 + tilesPerWave, nTiles);
    if (t0 >= t1) return;

    int gCur = -1; float racc[8];
#pragma unroll
    for (int jt = 0; jt < 8; ++jt) racc[jt] = 0.0f;

    for (int tile = t0; tile < t1; ++tile) {
        const int i0 = tile * 16;
        const int iA = min(i0 + lRow, N - 1);

        half8 afrag[KC];
#pragma unroll
        for (int kc = 0; kc < KCA; ++kc)
            afrag[kc] = *(const half8*)(hA + (size_t)iA * 128 + kc * 32 + lGrp * 8);
        if (H16) {
            const _Float16* hN = (const _Float16*)hNv;
#pragma unroll
            for (int kc = KCA; kc < KC; ++kc)
                afrag[kc] = *(const half8*)(hN + (size_t)iA * 128 + (kc - KCA) * 32 + lGrp * 8);
        } else {
            const float* hN = (const float*)hNv;
#pragma unroll
            for (int kc = KCA; kc < KC; ++kc) {
                const float* p = hN + (size_t)iA * 128 + (kc - KCA) * 32 + lGrp * 8;
                floatx4 f0 = *(const floatx4*)(p);
                floatx4 f1 = *(const floatx4*)(p + 4);
                half8 a;
#pragma unroll
                for (int i = 0; i < 4; ++i) { a[i] = f2h(f0[i]); a[i + 4] = f2h(f1[i]); }
                afrag[kc] = a;
            }
        }

        floatx4 acc[8] = {};
#pragma unroll
        for (int jt = 0; jt < 8; ++jt) {
            const int rb = (jt * 16 + lRow) * K2;
            const int sw = (jt * 16 + lRow) & 7;
#pragma unroll
            for (int kc = 0; kc < KC; ++kc) {
                half8 b = *(const half8*)(&lds[rb + (((kc * 4 + lGrp) ^ sw) * 8)]);
                acc[jt] = __builtin_amdgcn_mfma_f32_16x16x32_f16(afrag[kc], b, acc[jt], 0, 0, 0);
            }
        }

        if (L0) {
#pragma unroll
            for (int r = 0; r < 4; ++r) {
                const int i = min(i0 + lGrp * 4 + r, N - 1);
                const int g_t = gt[i];
#pragma unroll
                for (int jt = 0; jt < 8; ++jt)
                    acc[jt][r] += embW2[(size_t)g_t * 128 + jt * 16 + lRow];
            }
        }

        float scl[4];
#pragma unroll
        for (int r = 0; r < 4; ++r) {
            float s = 0.f;
#pragma unroll
            for (int jt = 0; jt < 8; ++jt) {
                float v = fmaxf(acc[jt][r], 0.0f);
                s += v * v;
            }
#pragma unroll
            for (int m = 1; m <= 8; m <<= 1) s += __shfl_xor(s, m);
            scl[r] = 1.0f / fmaxf(sqrtf(s), 1e-12f);
        }

#pragma unroll
        for (int r = 0; r < 4; ++r) {
            const int i = i0 + lGrp * 4 + r;
            if (i < N) {
#pragma unroll
                for (int jt = 0; jt < 8; ++jt) {
                    float v = fmaxf(acc[jt][r], 0.0f) * scl[r];
                    if (LAST) fOut[(size_t)i * 128 + jt * 16 + lRow] = v;
                    else      hOut[(size_t)i * 128 + jt * 16 + lRow] = f2h(v);
                }
            }
        }

        const int gFirst = n2g[min(i0, N - 1)];
        const int gLast  = n2g[min(i0 + 15, N - 1)];
        if (gFirst == gLast && i0 + 15 < N) {
            if (gFirst != gCur) {
                if (gCur >= 0 && lane < 16) {
#pragma unroll
                    for (int jt = 0; jt < 8; ++jt)
                        unsafeAtomicAdd(&readout[(size_t)gCur * 384 + layerOff + jt * 16 + lane], racc[jt]);
                }
                gCur = gFirst;
#pragma unroll
                for (int jt = 0; jt < 8; ++jt) racc[jt] = 0.0f;
            }
#pragma unroll
            for (int jt = 0; jt < 8; ++jt) {
                float t = 0.f;
#pragma unroll
                for (int r = 0; r < 4; ++r) t += fmaxf(acc[jt][r], 0.0f) * scl[r];
                t += __shfl_xor(t, 16);
                t += __shfl_xor(t, 32);
                racc[jt] += t;
            }
        } else {
            if (gCur >= 0 && lane < 16) {
#pragma unroll
                for (int jt = 0; jt < 8; ++jt)
                    unsafeAtomicAdd(&readout[(size_t)gCur * 384 + layerOff + jt * 16 + lane], racc[jt]);
            }
            gCur = -1;
#pragma unroll
            for (int jt = 0; jt < 8; ++jt) racc[jt] = 0.0f;
#pragma unroll
            for (int r = 0; r < 4; ++r) {
                const int i = i0 + lGrp * 4 + r;
                if (i < N) {
                    const int g = n2g[i];
#pragma unroll
                    for (int jt = 0; jt < 8; ++jt) {
                        float v = fmaxf(acc[jt][r], 0.0f) * scl[r];
                        unsafeAtomicAdd(&readout[(size_t)g * 384 + layerOff + jt * 16 + lRow], v);
                    }
                }
            }
        }
    }
    if (gCur >= 0 && lane < 16) {
#pragma unroll
        for (int jt = 0; jt < 8; ++jt)
            unsafeAtomicAdd(&readout[(size_t)gCur * 384 + layerOff + jt * 16 + lane], racc[jt]);
    }
}

// ---------------------------------------------------------------------------
extern "C" void kernel_launch(void* const* d_in, const int* in_sizes, int n_in,
                              void* d_out, int out_size, void* d_ws, size_t ws_size,
                              hipStream_t stream)
{
    const int*   gate_type = (const int*)d_in[0];
    const int*   src  = (const int*)d_in[1];
    const int*   dst  = (const int*)d_in[2];
    const float* wE   = (const float*)d_in[3];
    const int*   n2g  = (const int*)d_in[4];
    const float* emb  = (const float*)d_in[5];
    const float* W1_0 = (const float*)d_in[6];
    const float* b1_0 = (const float*)d_in[7];
    const float* W2_0 = (const float*)d_in[8];
    const float* W1_1 = (const float*)d_in[9];
    const float* b1_1 = (const float*)d_in[10];
    const float* W2_1 = (const float*)d_in[11];
    const float* W1_2 = (const float*)d_in[12];
    const float* b1_2 = (const float*)d_in[13];
    const float* W2_2 = (const float*)d_in[14];

    const int N = in_sizes[0];
    const int E = in_sizes[1];
    const int NGT = in_sizes[5] / 64;
    const int cap = (E + 3 * N + 15) & ~15;       // padded edge-slot capacity

    char* ws = (char*)d_ws;
    size_t off = 0;
    auto alloc = [&](size_t bytes) { void* p = ws + off; off = (off + bytes + 255) & ~255ULL; return p; };
    _Float16* hBuf  = (_Float16*)alloc(((size_t)N + 1) * 128 * 2);
    int*      srcS  = (int*)alloc(((size_t)cap + 16) * 4);
    int*      dstS  = (int*)alloc(((size_t)cap + 16) * 4);
    half4*    wS4   = (half4*)alloc(((size_t)cap + 16) * 8);
    int*      cnt   = (int*)alloc((size_t)N * 4);
    int*      offP  = (int*)alloc((size_t)N * 4);
    int*      cur   = (int*)alloc((size_t)N * 4);
    int*      bSums = (int*)alloc(256 * 4);
    _Float16* W1T1  = (_Float16*)alloc((size_t)128 * 136 * 2);
    _Float16* W1T2  = (_Float16*)alloc((size_t)128 * 136 * 2);
    _Float16* W2T0  = (_Float16*)alloc((size_t)128 * 128 * 2);
    _Float16* W2T1  = (_Float16*)alloc((size_t)128 * 256 * 2);
    _Float16* W2T2  = (_Float16*)alloc((size_t)128 * 256 * 2);
    float*    eW1b  = (float*)alloc((size_t)(NGT + 1) * 128 * 4);
    float*    eW2   = (float*)alloc((size_t)NGT * 128 * 4);
    size_t hn16_off = off;
    const bool h16 = (ws_size >= hn16_off + ((size_t)N + 1) * 128 * 2 + 256);
    _Float16* hN16 = (_Float16*)alloc(((size_t)N + 1) * 128 * 2);  // only if h16

    float* readout = (float*)d_out + (size_t)N * 128;  // [G,384]
    void*  hN      = h16 ? (void*)hN16 : (void*)d_out; // fp32 fallback in d_out

    const int eTiles4 = cap / 16;
    const int nTiles  = (N + 15) / 16;
    const int EB = 1024;                                // edge blocks, 4 waves ea
    const int tpwE = (eTiles4 + EB * 4 - 1) / (EB * 4);
    const int NB = 256;                                 // node blocks, 8 waves ea
    const int tpwN = (nTiles + NB * 8 - 1) / (NB * 8);
    const int nb = (N + 1023) / 1024;

    // ---- init + counting sort (padded to 4 per dst) ----
    hipMemsetAsync(cnt, 0, (size_t)N * 4, stream);
    hipMemsetAsync(cur, 0, (size_t)N * 4, stream);
    hipMemsetAsync(wS4, 0, ((size_t)cap + 16) * 8, stream);
    hipMemsetAsync(hBuf + (size_t)N * 128, 0, 256, stream);   // zero row N
    fill_dummy_kernel<<<(cap + 16 + 255) / 256, 256, 0, stream>>>(srcS, dstS, cap + 16, N, NGT);
    hist_kernel<<<(E + 255) / 256, 256, 0, stream>>>(dst, cnt, E);
    scan1p_kernel<<<nb, 256, 0, stream>>>(cnt, offP, N, bSums);
    scan2_kernel<<<1, 256, 0, stream>>>(bSums, nb);
    scan3_kernel<<<nb, 256, 0, stream>>>(offP, N, bSums);
    scatter_kernel<<<(E + 255) / 256, 256, 0, stream>>>(src, dst, wE, gate_type,
                                                        offP, cur, srcS, dstS, wS4, E);

    // ---- weight prep ----
    embW1_kernel<<<((NGT + 1) * 128 + 255) / 256, 256, 0, stream>>>(emb, W1_0, b1_0, eW1b, NGT);
    embW2_kernel<<<(NGT * 128 + 255) / 256, 256, 0, stream>>>(emb, W2_0, eW2, NGT);
    wprep_kernel<<<(128 * 136 + 255) / 256, 256, 0, stream>>>(W1_1, b1_1, W1T1, 131, 136);
    wprep_kernel<<<(128 * 136 + 255) / 256, 256, 0, stream>>>(W1_2, b1_2, W1T2, 131, 136);
    wprep_kernel<<<(128 * 128 + 255) / 256, 256, 0, stream>>>(W2_0 + (size_t)64 * 128, nullptr, W2T0, 128, 128);
    wprep_kernel<<<(128 * 256 + 255) / 256, 256, 0, stream>>>(W2_1, nullptr, W2T1, 256, 256);
    wprep_kernel<<<(128 * 256 + 255) / 256, 256, 0, stream>>>(W2_2, nullptr, W2T2, 256, 256);

    if (h16) {
        hipMemsetAsync(readout, 0, (size_t)(out_size - N * 128) * 4, stream);
        hipMemsetAsync(hN16, 0, ((size_t)N + 1) * 128 * 2, stream);
        // layer 0
        edge0_kernel<true><<<EB, 256, 0, stream>>>(eW1b, W1_0, srcS, dstS, wS4, hN, N, tpwE, eTiles4);
        node_kernel<true, true, false><<<NB, 512, 0, stream>>>(nullptr, hN, W2T0, eW2, gate_type, n2g,
                                                               hBuf, nullptr, readout, N, tpwN, nTiles, 0);
        hipMemsetAsync(hN16, 0, ((size_t)N + 1) * 128 * 2, stream);
        // layer 1
        edge_mfma_kernel<true><<<EB, 256, 0, stream>>>(hBuf, W1T1, srcS, dstS, wS4, hN, N, tpwE, eTiles4);
        node_kernel<true, false, false><<<NB, 512, 0, stream>>>(hBuf, hN, W2T1, nullptr, nullptr, n2g,
                                                                hBuf, nullptr, readout, N, tpwN, nTiles, 128);
        hipMemsetAsync(hN16, 0, ((size_t)N + 1) * 128 * 2, stream);
        // layer 2 (final fp32 h straight to d_out)
        edge_mfma_kernel<true><<<EB, 256, 0, stream>>>(hBuf, W1T2, srcS, dstS, wS4, hN, N, tpwE, eTiles4);
        node_kernel<true, false, true><<<NB, 512, 0, stream>>>(hBuf, hN, W2T2, nullptr, nullptr, n2g,
                                                               nullptr, (float*)d_out, readout, N, tpwN, nTiles, 256);
    } else {
        hipMemsetAsync(d_out, 0, (size_t)out_size * 4, stream);
        // layer 0
        edge0_kernel<false><<<EB, 256, 0, stream>>>(eW1b, W1_0, srcS, dstS, wS4, hN, N, tpwE, eTiles4);
        node_kernel<false, true, false><<<NB, 512, 0, stream>>>(nullptr, hN, W2T0, eW2, gate_type, n2g,
                                                                hBuf, nullptr, readout, N, tpwN, nTiles, 0);
        hipMemsetAsync(d_out, 0, (size_t)N * 128 * 4, stream);
        // layer 1
        edge_mfma_kernel<false><<<EB, 256, 0, stream>>>(hBuf, W1T1, srcS, dstS, wS4, hN, N, tpwE, eTiles4);
        node_kernel<false, false, false><<<NB, 512, 0, stream>>>(hBuf, hN, W2T1, nullptr, nullptr, n2g,
                                                                 hBuf, nullptr, readout, N, tpwN, nTiles, 128);
        hipMemsetAsync(d_out, 0, (size_t)N * 128 * 4, stream);
        // layer 2 (in-place over hN = d_out)
        edge_mfma_kernel<false><<<EB, 256, 0, stream>>>(hBuf, W1T2, srcS, dstS, wS4, hN, N, tpwE, eTiles4);
        node_kernel<false, false, true><<<NB, 512, 0, stream>>>(hBuf, hN, W2T2, nullptr, nullptr, n2g,
                                                                nullptr, (float*)d_out, readout, N, tpwN, nTiles, 256);
    }
}